// Round 2
// baseline (47.845 us; speedup 1.0000x reference)
//
#include <hip/hip_runtime.h>

#define BATCH 128
#define LEN 512
#define NCHUNK 8
#define CH_STEPS 64           // 8*64 = 512 >= 511; last chunk zero-padded
#define STEPS_TOTAL 511
#define SIG_DIM 4680          // 8 + 64 + 512 + 4096
#define N_OUT 10
#define OFF2 8
#define OFF3 72
#define OFF4 584

// ---------------------------------------------------------------------------
// Kernel 1: per-(batch, chunk) depth-4 signature of a sub-path via Chen scan.
// 512 threads; thread t owns (i,j,k) = (t>>6, (t>>3)&7, t&7):
//   s4[i][j][k][0..7] (8 regs), s3[i][j][k] (1 reg),
//   private copies of s2[i][j], s1[i]  -> no barriers in the step loop.
// Fixed 64 steps per chunk (zero increments are identity in tensor algebra),
// so the loop trip count is compile-time and LDS reads get imm offsets.
// ---------------------------------------------------------------------------
__global__ __launch_bounds__(512, 8) void sig_chunk_kernel(const float* __restrict__ X,
                                                           float* __restrict__ ws) {
    const int wg = blockIdx.x;          // b * NCHUNK + ch
    const int b  = wg >> 3;
    const int ch = wg & 7;
    const int s0 = ch * CH_STEPS;
    const int nst = min(CH_STEPS, STEPS_TOTAL - s0);
    const int t = threadIdx.x;

    __shared__ __align__(16) float dx[CH_STEPS * 8];   // 2 KB
    const float4* __restrict__ Xb4 =
        (const float4*)(X + (size_t)b * LEN * 8 + (size_t)s0 * 8);
    if (t < CH_STEPS * 2) {             // 128 float4 slots
        float4 d = make_float4(0.f, 0.f, 0.f, 0.f);
        if (t < nst * 2) {
            const float4 a = Xb4[t];
            const float4 c = Xb4[t + 2];
            d = make_float4(c.x - a.x, c.y - a.y, c.z - a.z, c.w - a.w);
        }
        ((float4*)dx)[t] = d;
    }
    __syncthreads();

    const int i = t >> 6, j = (t >> 3) & 7, k = t & 7;
    float s1v = 0.f, s2v = 0.f, s3v = 0.f;
    float s4v[8] = {0.f, 0.f, 0.f, 0.f, 0.f, 0.f, 0.f, 0.f};

    #pragma unroll 4
    for (int s = 0; s < CH_STEPS; ++s) {
        const float4 va = *(const float4*)&dx[s * 8];
        const float4 vb = *(const float4*)&dx[s * 8 + 4];
        const float vi = dx[s * 8 + i];
        const float vj = dx[s * 8 + j];
        const float vk = dx[s * 8 + k];

        // shared sub-expressions: t1 = s1*vj, p = vi*vj (old s1)
        const float t1 = s1v * vj;
        const float p  = vi * vj;
        // level-4 coeff: c0 = s3 + vk*(s2/2 + t1/6 + p/24)
        const float u  = fmaf(1.f / 24.f, p, fmaf(1.f / 6.f, t1, 0.5f * s2v));
        const float c0 = fmaf(vk, u, s3v);
        s4v[0] = fmaf(c0, va.x, s4v[0]);
        s4v[1] = fmaf(c0, va.y, s4v[1]);
        s4v[2] = fmaf(c0, va.z, s4v[2]);
        s4v[3] = fmaf(c0, va.w, s4v[3]);
        s4v[4] = fmaf(c0, vb.x, s4v[4]);
        s4v[5] = fmaf(c0, vb.y, s4v[5]);
        s4v[6] = fmaf(c0, vb.z, s4v[6]);
        s4v[7] = fmaf(c0, vb.w, s4v[7]);
        // level-3: s3 += vk*(s2 + t1/2 + p/6)
        const float w = fmaf(1.f / 6.f, p, fmaf(0.5f, t1, s2v));
        s3v = fmaf(vk, w, s3v);
        // level-2: s2 += t1 + p/2
        s2v = fmaf(0.5f, p, s2v + t1);
        // level-1
        s1v += vi;
    }

    float* __restrict__ o = ws + (size_t)wg * SIG_DIM;
    if ((t & 63) == 0) o[t >> 6] = s1v;                // s1[i]
    if ((t & 7) == 0)  o[OFF2 + (t >> 3)] = s2v;       // s2[ij]
    o[OFF3 + t] = s3v;
    *(float4*)&o[OFF4 + t * 8]     = make_float4(s4v[0], s4v[1], s4v[2], s4v[3]);
    *(float4*)&o[OFF4 + t * 8 + 4] = make_float4(s4v[4], s4v[5], s4v[6], s4v[7]);
}

// ---------------------------------------------------------------------------
// Kernel 2: per-batch Chen-combine of the NCHUNK chunk signatures + fused
// linear layer (sig @ W.T + b) with block reduction. Register-prefetch
// double buffer overlaps next-chunk global loads with the current combine.
// ---------------------------------------------------------------------------
#define SIG_V4 1170            // SIG_DIM / 4

__global__ __launch_bounds__(512) void sig_combine_linear(const float* __restrict__ ws,
                                                          const float* __restrict__ W,
                                                          const float* __restrict__ bias,
                                                          float* __restrict__ out) {
    const int b = blockIdx.x;
    const int t = threadIdx.x;
    const int i = t >> 6, j = (t >> 3) & 7, k = t & 7;
    const float* __restrict__ base = ws + (size_t)b * NCHUNK * SIG_DIM;

    // A := chunk 0 signature (per-thread ownership as in kernel 1)
    float A1 = base[i];
    float A2 = base[OFF2 + i * 8 + j];
    float A3 = base[OFF3 + t];
    const float4 a4a = *(const float4*)&base[OFF4 + t * 8];
    const float4 a4b = *(const float4*)&base[OFF4 + t * 8 + 4];
    float A4[8] = {a4a.x, a4a.y, a4a.z, a4a.w, a4b.x, a4b.y, a4b.z, a4b.w};

    __shared__ __align__(16) float Bs[SIG_DIM];

    // prefetch chunk 1 into registers
    float4 pre[3];
    {
        const float4* __restrict__ cp4 = (const float4*)(base + SIG_DIM);
        #pragma unroll
        for (int q = 0; q < 3; ++q) {
            const int idx = t + q * 512;
            if (idx < SIG_V4) pre[q] = cp4[idx];
        }
    }

    for (int c = 1; c < NCHUNK; ++c) {
        __syncthreads();                    // previous combine done reading Bs
        #pragma unroll
        for (int q = 0; q < 3; ++q) {
            const int idx = t + q * 512;
            if (idx < SIG_V4) ((float4*)Bs)[idx] = pre[q];
        }
        __syncthreads();

        if (c + 1 < NCHUNK) {               // issue next chunk's loads now
            const float4* __restrict__ cp4 =
                (const float4*)(base + (size_t)(c + 1) * SIG_DIM);
            #pragma unroll
            for (int q = 0; q < 3; ++q) {
                const int idx = t + q * 512;
                if (idx < SIG_V4) pre[q] = cp4[idx];
            }
        }

        const float B1i = Bs[i], B1j = Bs[j], B1k = Bs[k];
        const float4 b1a = *(const float4*)&Bs[0];
        const float4 b1b = *(const float4*)&Bs[4];
        const float B2ij = Bs[OFF2 + i * 8 + j];
        const float B2jk = Bs[OFF2 + j * 8 + k];
        const float4 b2a = *(const float4*)&Bs[OFF2 + k * 8];
        const float4 b2b = *(const float4*)&Bs[OFF2 + k * 8 + 4];
        const float B3ijk = Bs[OFF3 + t];
        const float4 b3a = *(const float4*)&Bs[OFF3 + (j * 8 + k) * 8];
        const float4 b3b = *(const float4*)&Bs[OFF3 + (j * 8 + k) * 8 + 4];
        const float4 b4a = *(const float4*)&Bs[OFF4 + t * 8];
        const float4 b4b = *(const float4*)&Bs[OFF4 + t * 8 + 4];

        // C4 = A4 + A3⊗B1 + A2⊗B2 + A1⊗B3 + B4   (old A1..A3)
        A4[0] += A3 * b1a.x + A2 * b2a.x + A1 * b3a.x + b4a.x;
        A4[1] += A3 * b1a.y + A2 * b2a.y + A1 * b3a.y + b4a.y;
        A4[2] += A3 * b1a.z + A2 * b2a.z + A1 * b3a.z + b4a.z;
        A4[3] += A3 * b1a.w + A2 * b2a.w + A1 * b3a.w + b4a.w;
        A4[4] += A3 * b1b.x + A2 * b2b.x + A1 * b3b.x + b4b.x;
        A4[5] += A3 * b1b.y + A2 * b2b.y + A1 * b3b.y + b4b.y;
        A4[6] += A3 * b1b.z + A2 * b2b.z + A1 * b3b.z + b4b.z;
        A4[7] += A3 * b1b.w + A2 * b2b.w + A1 * b3b.w + b4b.w;
        // C3 = A3 + A2⊗B1 + A1⊗B2 + B3
        A3 += A2 * B1k + A1 * B2jk + B3ijk;
        // C2 = A2 + A1⊗B1 + B2
        A2 += A1 * B1j + B2ij;
        // C1
        A1 += B1i;
    }

    // Fused linear: out[b][n] = sum_d sig[d] * W[n][d] + bias[n]
    float part[N_OUT];
    #pragma unroll
    for (int n = 0; n < N_OUT; ++n) {
        const float* __restrict__ Wn = W + (size_t)n * SIG_DIM;
        float p = A3 * Wn[OFF3 + t];
        const float4 w4a = *(const float4*)&Wn[OFF4 + t * 8];
        const float4 w4b = *(const float4*)&Wn[OFF4 + t * 8 + 4];
        p = fmaf(A4[0], w4a.x, p);
        p = fmaf(A4[1], w4a.y, p);
        p = fmaf(A4[2], w4a.z, p);
        p = fmaf(A4[3], w4a.w, p);
        p = fmaf(A4[4], w4b.x, p);
        p = fmaf(A4[5], w4b.y, p);
        p = fmaf(A4[6], w4b.z, p);
        p = fmaf(A4[7], w4b.w, p);
        if ((t & 7) == 0)  p = fmaf(A2, Wn[OFF2 + (t >> 3)], p);  // canonical s2 owner
        if ((t & 63) == 0) p = fmaf(A1, Wn[t >> 6], p);           // canonical s1 owner
        part[n] = p;
    }

    // wave reduce (64 lanes) then cross-wave via LDS
    #pragma unroll
    for (int n = 0; n < N_OUT; ++n) {
        #pragma unroll
        for (int off = 32; off > 0; off >>= 1)
            part[n] += __shfl_xor(part[n], off, 64);
    }
    __shared__ float red[8][N_OUT];
    const int wv = t >> 6, ln = t & 63;
    if (ln == 0) {
        #pragma unroll
        for (int n = 0; n < N_OUT; ++n) red[wv][n] = part[n];
    }
    __syncthreads();
    if (t < N_OUT) {
        float s = bias[t];
        #pragma unroll
        for (int w = 0; w < 8; ++w) s += red[w][t];
        out[b * N_OUT + t] = s;
    }
}

extern "C" void kernel_launch(void* const* d_in, const int* in_sizes, int n_in,
                              void* d_out, int out_size, void* d_ws, size_t ws_size,
                              hipStream_t stream) {
    const float* X    = (const float*)d_in[0];
    const float* W    = (const float*)d_in[1];
    const float* bias = (const float*)d_in[2];
    float* out = (float*)d_out;
    float* ws  = (float*)d_ws;   // uses NCHUNK*BATCH*SIG_DIM*4 ≈ 19.2 MB

    hipLaunchKernelGGL(sig_chunk_kernel, dim3(BATCH * NCHUNK), dim3(512), 0, stream, X, ws);
    hipLaunchKernelGGL(sig_combine_linear, dim3(BATCH), dim3(512), 0, stream, ws, W, bias, out);
}

// Round 3
// 47.025 us; speedup vs baseline: 1.0174x; 1.0174x over previous
//
#include <hip/hip_runtime.h>

#define BATCH 128
#define LEN 512
#define NCHUNK 8
#define CH_STEPS 64           // 8*64 = 512 >= 511; last chunk zero-padded
#define STEPS_TOTAL 511
#define SIG_DIM 4680          // 8 + 64 + 512 + 4096
#define N_OUT 10
#define OFF2 8
#define OFF3 72
#define OFF4 584

// ---------------------------------------------------------------------------
// Kernel 1: per-(batch, chunk) depth-4 signature of a sub-path via Chen scan.
// 512 threads; thread t owns (i,j,k) = (t>>6, (t>>3)&7, t&7):
//   s4[i][j][k][0..7] (8 regs), s3[i][j][k] (1 reg),
//   private copies of s2[i][j], s1[i]  -> no barriers in the step loop.
// Fixed 64 steps per chunk (zero increments are identity in tensor algebra),
// so the loop trip count is compile-time and LDS reads get imm offsets.
// ---------------------------------------------------------------------------
__global__ __launch_bounds__(512, 8) void sig_chunk_kernel(const float* __restrict__ X,
                                                           float* __restrict__ ws) {
    const int wg = blockIdx.x;          // b * NCHUNK + ch
    const int b  = wg >> 3;
    const int ch = wg & 7;
    const int s0 = ch * CH_STEPS;
    const int nst = min(CH_STEPS, STEPS_TOTAL - s0);
    const int t = threadIdx.x;

    __shared__ __align__(16) float dx[CH_STEPS * 8];   // 2 KB
    const float4* __restrict__ Xb4 =
        (const float4*)(X + (size_t)b * LEN * 8 + (size_t)s0 * 8);
    if (t < CH_STEPS * 2) {             // 128 float4 slots
        float4 d = make_float4(0.f, 0.f, 0.f, 0.f);
        if (t < nst * 2) {
            const float4 a = Xb4[t];
            const float4 c = Xb4[t + 2];
            d = make_float4(c.x - a.x, c.y - a.y, c.z - a.z, c.w - a.w);
        }
        ((float4*)dx)[t] = d;
    }
    __syncthreads();

    const int i = t >> 6, j = (t >> 3) & 7, k = t & 7;
    float s1v = 0.f, s2v = 0.f, s3v = 0.f;
    float s4v[8] = {0.f, 0.f, 0.f, 0.f, 0.f, 0.f, 0.f, 0.f};

    #pragma unroll 4
    for (int s = 0; s < CH_STEPS; ++s) {
        const float4 va = *(const float4*)&dx[s * 8];
        const float4 vb = *(const float4*)&dx[s * 8 + 4];
        const float vi = dx[s * 8 + i];
        const float vj = dx[s * 8 + j];
        const float vk = dx[s * 8 + k];

        // shared sub-expressions: t1 = s1*vj, p = vi*vj (old s1)
        const float t1 = s1v * vj;
        const float p  = vi * vj;
        // level-4 coeff: c0 = s3 + vk*(s2/2 + t1/6 + p/24)
        const float u  = fmaf(1.f / 24.f, p, fmaf(1.f / 6.f, t1, 0.5f * s2v));
        const float c0 = fmaf(vk, u, s3v);
        s4v[0] = fmaf(c0, va.x, s4v[0]);
        s4v[1] = fmaf(c0, va.y, s4v[1]);
        s4v[2] = fmaf(c0, va.z, s4v[2]);
        s4v[3] = fmaf(c0, va.w, s4v[3]);
        s4v[4] = fmaf(c0, vb.x, s4v[4]);
        s4v[5] = fmaf(c0, vb.y, s4v[5]);
        s4v[6] = fmaf(c0, vb.z, s4v[6]);
        s4v[7] = fmaf(c0, vb.w, s4v[7]);
        // level-3: s3 += vk*(s2 + t1/2 + p/6)
        const float w = fmaf(1.f / 6.f, p, fmaf(0.5f, t1, s2v));
        s3v = fmaf(vk, w, s3v);
        // level-2: s2 += t1 + p/2
        s2v = fmaf(0.5f, p, s2v + t1);
        // level-1
        s1v += vi;
    }

    float* __restrict__ o = ws + (size_t)wg * SIG_DIM;
    if ((t & 63) == 0) o[t >> 6] = s1v;                // s1[i]
    if ((t & 7) == 0)  o[OFF2 + (t >> 3)] = s2v;       // s2[ij]
    o[OFF3 + t] = s3v;
    *(float4*)&o[OFF4 + t * 8]     = make_float4(s4v[0], s4v[1], s4v[2], s4v[3]);
    *(float4*)&o[OFF4 + t * 8 + 4] = make_float4(s4v[4], s4v[5], s4v[6], s4v[7]);
}

// ---------------------------------------------------------------------------
// Kernel 2: per-batch Chen-combine of the NCHUNK chunk signatures + fused
// linear layer (sig @ W.T + b) with block reduction. Register-prefetch
// double buffer overlaps next-chunk global loads with the current combine.
// ---------------------------------------------------------------------------
#define SIG_V4 1170            // SIG_DIM / 4

__global__ __launch_bounds__(512) void sig_combine_linear(const float* __restrict__ ws,
                                                          const float* __restrict__ W,
                                                          const float* __restrict__ bias,
                                                          float* __restrict__ out) {
    const int b = blockIdx.x;
    const int t = threadIdx.x;
    const int i = t >> 6, j = (t >> 3) & 7, k = t & 7;
    const float* __restrict__ base = ws + (size_t)b * NCHUNK * SIG_DIM;

    // A := chunk 0 signature (per-thread ownership as in kernel 1)
    float A1 = base[i];
    float A2 = base[OFF2 + i * 8 + j];
    float A3 = base[OFF3 + t];
    const float4 a4a = *(const float4*)&base[OFF4 + t * 8];
    const float4 a4b = *(const float4*)&base[OFF4 + t * 8 + 4];
    float A4[8] = {a4a.x, a4a.y, a4a.z, a4a.w, a4b.x, a4b.y, a4b.z, a4b.w};

    __shared__ __align__(16) float Bs[SIG_DIM];

    // prefetch chunk 1 into registers
    float4 pre[3];
    {
        const float4* __restrict__ cp4 = (const float4*)(base + SIG_DIM);
        #pragma unroll
        for (int q = 0; q < 3; ++q) {
            const int idx = t + q * 512;
            if (idx < SIG_V4) pre[q] = cp4[idx];
        }
    }

    for (int c = 1; c < NCHUNK; ++c) {
        __syncthreads();                    // previous combine done reading Bs
        #pragma unroll
        for (int q = 0; q < 3; ++q) {
            const int idx = t + q * 512;
            if (idx < SIG_V4) ((float4*)Bs)[idx] = pre[q];
        }
        __syncthreads();

        if (c + 1 < NCHUNK) {               // issue next chunk's loads now
            const float4* __restrict__ cp4 =
                (const float4*)(base + (size_t)(c + 1) * SIG_DIM);
            #pragma unroll
            for (int q = 0; q < 3; ++q) {
                const int idx = t + q * 512;
                if (idx < SIG_V4) pre[q] = cp4[idx];
            }
        }

        const float B1i = Bs[i], B1j = Bs[j], B1k = Bs[k];
        const float4 b1a = *(const float4*)&Bs[0];
        const float4 b1b = *(const float4*)&Bs[4];
        const float B2ij = Bs[OFF2 + i * 8 + j];
        const float B2jk = Bs[OFF2 + j * 8 + k];
        const float4 b2a = *(const float4*)&Bs[OFF2 + k * 8];
        const float4 b2b = *(const float4*)&Bs[OFF2 + k * 8 + 4];
        const float B3ijk = Bs[OFF3 + t];
        const float4 b3a = *(const float4*)&Bs[OFF3 + (j * 8 + k) * 8];
        const float4 b3b = *(const float4*)&Bs[OFF3 + (j * 8 + k) * 8 + 4];
        const float4 b4a = *(const float4*)&Bs[OFF4 + t * 8];
        const float4 b4b = *(const float4*)&Bs[OFF4 + t * 8 + 4];

        // C4 = A4 + A3⊗B1 + A2⊗B2 + A1⊗B3 + B4   (old A1..A3)
        A4[0] += A3 * b1a.x + A2 * b2a.x + A1 * b3a.x + b4a.x;
        A4[1] += A3 * b1a.y + A2 * b2a.y + A1 * b3a.y + b4a.y;
        A4[2] += A3 * b1a.z + A2 * b2a.z + A1 * b3a.z + b4a.z;
        A4[3] += A3 * b1a.w + A2 * b2a.w + A1 * b3a.w + b4a.w;
        A4[4] += A3 * b1b.x + A2 * b2b.x + A1 * b3b.x + b4b.x;
        A4[5] += A3 * b1b.y + A2 * b2b.y + A1 * b3b.y + b4b.y;
        A4[6] += A3 * b1b.z + A2 * b2b.z + A1 * b3b.z + b4b.z;
        A4[7] += A3 * b1b.w + A2 * b2b.w + A1 * b3b.w + b4b.w;
        // C3 = A3 + A2⊗B1 + A1⊗B2 + B3
        A3 += A2 * B1k + A1 * B2jk + B3ijk;
        // C2 = A2 + A1⊗B1 + B2
        A2 += A1 * B1j + B2ij;
        // C1
        A1 += B1i;
    }

    // Fused linear: out[b][n] = sum_d sig[d] * W[n][d] + bias[n]
    float part[N_OUT];
    #pragma unroll
    for (int n = 0; n < N_OUT; ++n) {
        const float* __restrict__ Wn = W + (size_t)n * SIG_DIM;
        float p = A3 * Wn[OFF3 + t];
        const float4 w4a = *(const float4*)&Wn[OFF4 + t * 8];
        const float4 w4b = *(const float4*)&Wn[OFF4 + t * 8 + 4];
        p = fmaf(A4[0], w4a.x, p);
        p = fmaf(A4[1], w4a.y, p);
        p = fmaf(A4[2], w4a.z, p);
        p = fmaf(A4[3], w4a.w, p);
        p = fmaf(A4[4], w4b.x, p);
        p = fmaf(A4[5], w4b.y, p);
        p = fmaf(A4[6], w4b.z, p);
        p = fmaf(A4[7], w4b.w, p);
        if ((t & 7) == 0)  p = fmaf(A2, Wn[OFF2 + (t >> 3)], p);  // canonical s2 owner
        if ((t & 63) == 0) p = fmaf(A1, Wn[t >> 6], p);           // canonical s1 owner
        part[n] = p;
    }

    // wave reduce (64 lanes) then cross-wave via LDS
    #pragma unroll
    for (int n = 0; n < N_OUT; ++n) {
        #pragma unroll
        for (int off = 32; off > 0; off >>= 1)
            part[n] += __shfl_xor(part[n], off, 64);
    }
    __shared__ float red[8][N_OUT];
    const int wv = t >> 6, ln = t & 63;
    if (ln == 0) {
        #pragma unroll
        for (int n = 0; n < N_OUT; ++n) red[wv][n] = part[n];
    }
    __syncthreads();
    if (t < N_OUT) {
        float s = bias[t];
        #pragma unroll
        for (int w = 0; w < 8; ++w) s += red[w][t];
        out[b * N_OUT + t] = s;
    }
}

extern "C" void kernel_launch(void* const* d_in, const int* in_sizes, int n_in,
                              void* d_out, int out_size, void* d_ws, size_t ws_size,
                              hipStream_t stream) {
    const float* X    = (const float*)d_in[0];
    const float* W    = (const float*)d_in[1];
    const float* bias = (const float*)d_in[2];
    float* out = (float*)d_out;
    float* ws  = (float*)d_ws;   // uses NCHUNK*BATCH*SIG_DIM*4 ≈ 19.2 MB

    hipLaunchKernelGGL(sig_chunk_kernel, dim3(BATCH * NCHUNK), dim3(512), 0, stream, X, ws);
    hipLaunchKernelGGL(sig_combine_linear, dim3(BATCH), dim3(512), 0, stream, ws, W, bias, out);
}

// Round 4
// 41.784 us; speedup vs baseline: 1.1451x; 1.1254x over previous
//
#include <hip/hip_runtime.h>

#define BATCH 128
#define LEN 512
#define NCHUNK 4
#define CH_STEPS 128          // 4*128 = 512 >= 511; last step zero-padded
#define STEPS_TOTAL 511
#define SIG_DIM 4680          // 8 + 64 + 512 + 4096
#define N_OUT 10
#define OFF2 8
#define OFF3 72
#define OFF4 584
#define DXG_ELEMS (BATCH * NCHUNK * CH_STEPS * 8)   // 524288 floats = 2 MB

// ---------------------------------------------------------------------------
// Kernel 0: dx[b][ch][sl][0..7] = X[b][s+1]-X[b][s] (0 past the end).
// Gives kernel 1 a global copy it can read through the SCALAR (SMEM) pipe.
// ---------------------------------------------------------------------------
__global__ __launch_bounds__(512) void dx_kernel(const float* __restrict__ X,
                                                 float* __restrict__ dxg) {
    const int gid = blockIdx.x * 512 + threadIdx.x;   // one thread per (b, sg)
    const int b = gid >> 9, sg = gid & 511;
    float4 d0 = make_float4(0.f, 0.f, 0.f, 0.f);
    float4 d1 = d0;
    if (sg < STEPS_TOTAL) {
        const float4* xp = (const float4*)(X + ((size_t)b * LEN + sg) * 8);
        const float4 a0 = xp[0], a1 = xp[1], c0 = xp[2], c1 = xp[3];
        d0 = make_float4(c0.x - a0.x, c0.y - a0.y, c0.z - a0.z, c0.w - a0.w);
        d1 = make_float4(c1.x - a1.x, c1.y - a1.y, c1.z - a1.z, c1.w - a1.w);
    }
    float4* o = (float4*)(dxg + (size_t)gid * 8);     // [b][ch][sl][8] contiguous
    o[0] = d0;
    o[1] = d1;
}

// ---------------------------------------------------------------------------
// Kernel 1: per-(batch, chunk) depth-4 signature via Chen scan.
// Thread t owns (i,j,k) = (t>>6, (t>>3)&7, t&7).
// va/vb (block-uniform) come from SGPRs via uniform scalar loads; vi is
// wave-uniform (i == wave id) -> scalar load; only vj/vk touch LDS
// (2x ds_read_b32 broadcast per step instead of 2x b128 + 3x b32).
// ---------------------------------------------------------------------------
__global__ __launch_bounds__(512) void sig_chunk_kernel(const float* __restrict__ dxg,
                                                        float* __restrict__ sig) {
    const int wg = blockIdx.x;          // b * NCHUNK + ch
    const int t = threadIdx.x;

    __shared__ __align__(16) float dxs[CH_STEPS * 8];   // 4 KB
    const float4* __restrict__ g4 = (const float4*)(dxg + (size_t)wg * CH_STEPS * 8);
    if (t < CH_STEPS * 2) ((float4*)dxs)[t] = g4[t];
    __syncthreads();

    const int i = t >> 6, j = (t >> 3) & 7, k = t & 7;
    // wave-uniform scalar bases (readfirstlane -> SGPR -> SMEM loads)
    const int ubase = __builtin_amdgcn_readfirstlane(wg * (CH_STEPS * 8));
    const int si    = __builtin_amdgcn_readfirstlane(i);
    const float* __restrict__ du = dxg + ubase;
    const float* __restrict__ dui = dxg + ubase + si;

    float s1v = 0.f, s2v = 0.f, s3v = 0.f;
    float s4v[8] = {0.f, 0.f, 0.f, 0.f, 0.f, 0.f, 0.f, 0.f};

    #pragma unroll 4
    for (int s = 0; s < CH_STEPS; ++s) {
        // block-uniform increments -> SGPRs (s_load_dwordx8 expected)
        const float a0 = du[s * 8 + 0], a1 = du[s * 8 + 1];
        const float a2 = du[s * 8 + 2], a3 = du[s * 8 + 3];
        const float a4 = du[s * 8 + 4], a5 = du[s * 8 + 5];
        const float a6 = du[s * 8 + 6], a7 = du[s * 8 + 7];
        const float vi = dui[s * 8];          // wave-uniform scalar
        const float vj = dxs[s * 8 + j];      // LDS broadcast (8 banks)
        const float vk = dxs[s * 8 + k];      // LDS broadcast

        const float t1 = s1v * vj;
        const float p  = vi * vj;
        // level-4 coeff: c0 = s3 + vk*(s2/2 + t1/6 + p/24)
        const float u  = fmaf(1.f / 24.f, p, fmaf(1.f / 6.f, t1, 0.5f * s2v));
        const float c0 = fmaf(vk, u, s3v);
        s4v[0] = fmaf(c0, a0, s4v[0]);
        s4v[1] = fmaf(c0, a1, s4v[1]);
        s4v[2] = fmaf(c0, a2, s4v[2]);
        s4v[3] = fmaf(c0, a3, s4v[3]);
        s4v[4] = fmaf(c0, a4, s4v[4]);
        s4v[5] = fmaf(c0, a5, s4v[5]);
        s4v[6] = fmaf(c0, a6, s4v[6]);
        s4v[7] = fmaf(c0, a7, s4v[7]);
        // level-3: s3 += vk*(s2 + t1/2 + p/6)
        const float w = fmaf(1.f / 6.f, p, fmaf(0.5f, t1, s2v));
        s3v = fmaf(vk, w, s3v);
        // level-2: s2 += t1 + p/2
        s2v = fmaf(0.5f, p, s2v + t1);
        // level-1
        s1v += vi;
    }

    float* __restrict__ o = sig + (size_t)wg * SIG_DIM;
    if ((t & 63) == 0) o[t >> 6] = s1v;                // s1[i]
    if ((t & 7) == 0)  o[OFF2 + (t >> 3)] = s2v;       // s2[ij]
    o[OFF3 + t] = s3v;
    *(float4*)&o[OFF4 + t * 8]     = make_float4(s4v[0], s4v[1], s4v[2], s4v[3]);
    *(float4*)&o[OFF4 + t * 8 + 4] = make_float4(s4v[4], s4v[5], s4v[6], s4v[7]);
}

// ---------------------------------------------------------------------------
// Kernel 2: per-batch Chen-combine of the NCHUNK chunk signatures + fused
// linear layer (sig @ W.T + b) with block reduction.
// ---------------------------------------------------------------------------
#define SIG_V4 1170            // SIG_DIM / 4

__global__ __launch_bounds__(512) void sig_combine_linear(const float* __restrict__ ws,
                                                          const float* __restrict__ W,
                                                          const float* __restrict__ bias,
                                                          float* __restrict__ out) {
    const int b = blockIdx.x;
    const int t = threadIdx.x;
    const int i = t >> 6, j = (t >> 3) & 7, k = t & 7;
    const float* __restrict__ base = ws + (size_t)b * NCHUNK * SIG_DIM;

    // A := chunk 0 signature (per-thread ownership as in kernel 1)
    float A1 = base[i];
    float A2 = base[OFF2 + i * 8 + j];
    float A3 = base[OFF3 + t];
    const float4 a4a = *(const float4*)&base[OFF4 + t * 8];
    const float4 a4b = *(const float4*)&base[OFF4 + t * 8 + 4];
    float A4[8] = {a4a.x, a4a.y, a4a.z, a4a.w, a4b.x, a4b.y, a4b.z, a4b.w};

    __shared__ __align__(16) float Bs[SIG_DIM];

    // prefetch chunk 1 into registers
    float4 pre[3];
    {
        const float4* __restrict__ cp4 = (const float4*)(base + SIG_DIM);
        #pragma unroll
        for (int q = 0; q < 3; ++q) {
            const int idx = t + q * 512;
            if (idx < SIG_V4) pre[q] = cp4[idx];
        }
    }

    for (int c = 1; c < NCHUNK; ++c) {
        __syncthreads();                    // previous combine done reading Bs
        #pragma unroll
        for (int q = 0; q < 3; ++q) {
            const int idx = t + q * 512;
            if (idx < SIG_V4) ((float4*)Bs)[idx] = pre[q];
        }
        __syncthreads();

        if (c + 1 < NCHUNK) {               // issue next chunk's loads now
            const float4* __restrict__ cp4 =
                (const float4*)(base + (size_t)(c + 1) * SIG_DIM);
            #pragma unroll
            for (int q = 0; q < 3; ++q) {
                const int idx = t + q * 512;
                if (idx < SIG_V4) pre[q] = cp4[idx];
            }
        }

        const float B1i = Bs[i], B1j = Bs[j], B1k = Bs[k];
        const float4 b1a = *(const float4*)&Bs[0];
        const float4 b1b = *(const float4*)&Bs[4];
        const float B2ij = Bs[OFF2 + i * 8 + j];
        const float B2jk = Bs[OFF2 + j * 8 + k];
        const float4 b2a = *(const float4*)&Bs[OFF2 + k * 8];
        const float4 b2b = *(const float4*)&Bs[OFF2 + k * 8 + 4];
        const float B3ijk = Bs[OFF3 + t];
        const float4 b3a = *(const float4*)&Bs[OFF3 + (j * 8 + k) * 8];
        const float4 b3b = *(const float4*)&Bs[OFF3 + (j * 8 + k) * 8 + 4];
        const float4 b4a = *(const float4*)&Bs[OFF4 + t * 8];
        const float4 b4b = *(const float4*)&Bs[OFF4 + t * 8 + 4];

        // C4 = A4 + A3⊗B1 + A2⊗B2 + A1⊗B3 + B4   (old A1..A3)
        A4[0] += A3 * b1a.x + A2 * b2a.x + A1 * b3a.x + b4a.x;
        A4[1] += A3 * b1a.y + A2 * b2a.y + A1 * b3a.y + b4a.y;
        A4[2] += A3 * b1a.z + A2 * b2a.z + A1 * b3a.z + b4a.z;
        A4[3] += A3 * b1a.w + A2 * b2a.w + A1 * b3a.w + b4a.w;
        A4[4] += A3 * b1b.x + A2 * b2b.x + A1 * b3b.x + b4b.x;
        A4[5] += A3 * b1b.y + A2 * b2b.y + A1 * b3b.y + b4b.y;
        A4[6] += A3 * b1b.z + A2 * b2b.z + A1 * b3b.z + b4b.z;
        A4[7] += A3 * b1b.w + A2 * b2b.w + A1 * b3b.w + b4b.w;
        // C3 = A3 + A2⊗B1 + A1⊗B2 + B3
        A3 += A2 * B1k + A1 * B2jk + B3ijk;
        // C2 = A2 + A1⊗B1 + B2
        A2 += A1 * B1j + B2ij;
        // C1
        A1 += B1i;
    }

    // Fused linear: out[b][n] = sum_d sig[d] * W[n][d] + bias[n]
    float part[N_OUT];
    #pragma unroll
    for (int n = 0; n < N_OUT; ++n) {
        const float* __restrict__ Wn = W + (size_t)n * SIG_DIM;
        float p = A3 * Wn[OFF3 + t];
        const float4 w4a = *(const float4*)&Wn[OFF4 + t * 8];
        const float4 w4b = *(const float4*)&Wn[OFF4 + t * 8 + 4];
        p = fmaf(A4[0], w4a.x, p);
        p = fmaf(A4[1], w4a.y, p);
        p = fmaf(A4[2], w4a.z, p);
        p = fmaf(A4[3], w4a.w, p);
        p = fmaf(A4[4], w4b.x, p);
        p = fmaf(A4[5], w4b.y, p);
        p = fmaf(A4[6], w4b.z, p);
        p = fmaf(A4[7], w4b.w, p);
        if ((t & 7) == 0)  p = fmaf(A2, Wn[OFF2 + (t >> 3)], p);  // canonical s2 owner
        if ((t & 63) == 0) p = fmaf(A1, Wn[t >> 6], p);           // canonical s1 owner
        part[n] = p;
    }

    // wave reduce (64 lanes) then cross-wave via LDS
    #pragma unroll
    for (int n = 0; n < N_OUT; ++n) {
        #pragma unroll
        for (int off = 32; off > 0; off >>= 1)
            part[n] += __shfl_xor(part[n], off, 64);
    }
    __shared__ float red[8][N_OUT];
    const int wv = t >> 6, ln = t & 63;
    if (ln == 0) {
        #pragma unroll
        for (int n = 0; n < N_OUT; ++n) red[wv][n] = part[n];
    }
    __syncthreads();
    if (t < N_OUT) {
        float s = bias[t];
        #pragma unroll
        for (int w = 0; w < 8; ++w) s += red[w][t];
        out[b * N_OUT + t] = s;
    }
}

extern "C" void kernel_launch(void* const* d_in, const int* in_sizes, int n_in,
                              void* d_out, int out_size, void* d_ws, size_t ws_size,
                              hipStream_t stream) {
    const float* X    = (const float*)d_in[0];
    const float* W    = (const float*)d_in[1];
    const float* bias = (const float*)d_in[2];
    float* out = (float*)d_out;
    float* dxg = (float*)d_ws;                 // 2 MB
    float* sig = (float*)d_ws + DXG_ELEMS;     // 9.6 MB

    hipLaunchKernelGGL(dx_kernel, dim3(BATCH * LEN / 512), dim3(512), 0, stream, X, dxg);
    hipLaunchKernelGGL(sig_chunk_kernel, dim3(BATCH * NCHUNK), dim3(512), 0, stream, dxg, sig);
    hipLaunchKernelGGL(sig_combine_linear, dim3(BATCH), dim3(512), 0, stream, sig, W, bias, out);
}